// Round 5
// baseline (9573.708 us; speedup 1.0000x reference)
//
#include <hip/hip_runtime.h>

// ---------------------------------------------------------------------------
// BBCU binary SR network, round 16.
// R15 post-mortem: hand-rolled grid barrier correct but ~68us/layer (agent
// fences = L2 writeback/inv on non-coherent XCD L2s). Fused body reverted to
// R13's proven 32-dispatch form (~20us/layer).
// This round:
//   * up1/up2 write NHWC feature maps (restructured channel loop -> float4
//     stores; per-channel conv is INTEGER so reorder is exact).
//   * hr + conv_last re-fused (R12-proven numerics) with NHWC U residual:
//     kills R12's two failure modes (channel gather 1.7GB FETCH, 256-VGPR
//     spill 2GB WRITE) and deletes the V buffer + 4 dispatches.
//   * up1 batched over samples (one dispatch).
// ws: A[0,16) B[16,32)(body pong, dead before up1) Pbat[16,80) U[80,144)
//     bitsA/B[144,145) bits256[145,147) bits512[147,149) wbits[149,..)
//     scales[150,..)
// ---------------------------------------------------------------------------

typedef unsigned long long u64;
typedef unsigned int u32;
typedef unsigned short u16;

__device__ inline float fadd(float a, float b) { return __fadd_rn(a, b); }
__device__ inline float fmul(float a, float b) { return __fmul_rn(a, b); }

// numpy pairwise sum of |p[0..n)| (exact numpy algorithm, f32) — for scale
__device__ float pw_abs_sum(const float* p, int n) {
  if (n <= 8) {
    float s = fabsf(p[0]);
    for (int i = 1; i < n; i++) s = fadd(s, fabsf(p[i]));
    return s;
  }
  if (n <= 128) {
    float r[8];
#pragma unroll
    for (int q = 0; q < 8; q++) r[q] = fabsf(p[q]);
    int i;
    for (i = 8; i + 8 <= n; i += 8)
#pragma unroll
      for (int q = 0; q < 8; q++) r[q] = fadd(r[q], fabsf(p[i + q]));
    float res = fadd(fadd(fadd(r[0], r[1]), fadd(r[2], r[3])),
                     fadd(fadd(r[4], r[5]), fadd(r[6], r[7])));
    for (; i < n; i++) res = fadd(res, fabsf(p[i]));
    return res;
  }
  int n2 = (n / 2) & ~7;
  return fadd(pw_abs_sum(p, n2), pw_abs_sum(p + n2, n - n2));
}

// --- diagnostic ------------------------------------------------------------
__global__ __launch_bounds__(256) void diag_kernel(float* __restrict__ out,
                                                   int n, float tag) {
  int idx = blockIdx.x * 256 + threadIdx.x;
  if (idx < n) out[idx] = (idx == 0) ? tag : 0.f;
}

// --- weight prep: scale (numpy pairwise mean|w|) + 9 x u64 sign bits -------
__global__ __launch_bounds__(64) void binw_pack_kernel(
    const float* __restrict__ w, u64* __restrict__ wbits,
    float* __restrict__ scale, int nch) {
  int ch = blockIdx.x * 64 + threadIdx.x;
  if (ch >= nch) return;
  const float* wc = w + (size_t)ch * 576;
  float S = pw_abs_sum(wc, 576);
  scale[ch] = __fdiv_rn(S, 576.0f);
  u64 b[9] = {0, 0, 0, 0, 0, 0, 0, 0, 0};
  for (int ci = 0; ci < 64; ci++) {
#pragma unroll
    for (int tap = 0; tap < 9; tap++)
      b[tap] |= (u64)(wc[ci * 9 + tap] > 0.0f) << ci;
  }
#pragma unroll
  for (int tap = 0; tap < 9; tap++) wbits[(size_t)ch * 9 + tap] = b[tap];
}

// --- conv_first, batched over samples (blockIdx.y = n) ---------------------
__global__ __launch_bounds__(256) void conv_first_kernel(
    const float* __restrict__ x,      // (4,3,128,128)
    const float* __restrict__ w, const float* __restrict__ b,
    float* __restrict__ out) {        // (4,64,128,128)
  int n = blockIdx.y;
  const float* xn = x + (size_t)n * 49152;
  float* on = out + (size_t)n * 1048576;
  int idx = blockIdx.x * 256 + threadIdx.x;
  int gx = idx & 127;
  int gy = (idx >> 7) & 127;
  int co = idx >> 14;
  const float* wp = w + co * 27;
  float acc = 0.f;
  for (int ky = 0; ky < 3; ky++) {
    int yy = gy + ky - 1;
    if (yy < 0 || yy > 127) continue;
    for (int kx = 0; kx < 3; kx++) {
      int xx = gx + kx - 1;
      if (xx < 0 || xx > 127) continue;
      for (int ci = 0; ci < 3; ci++)
        acc = fmaf(xn[ci * 16384 + yy * 128 + xx],
                   wp[ci * 9 + ky * 3 + kx], acc);
    }
  }
  float wb = fadd(acc, b[co]);
  on[idx] = wb >= 0.f ? wb : fmul(0.1f, wb);
}

// --- pack: 64ch f32 + move -> u64 sign bits per pixel (batched) ------------
__global__ __launch_bounds__(256) void pack_kernel(
    const float* __restrict__ feat, const float* __restrict__ move,
    u64* __restrict__ bits) {
  int n = blockIdx.y;
  const float* f = feat + (size_t)n * 1048576;
  u64* bo = bits + (size_t)n * 16384;
  int pix = blockIdx.x * 256 + threadIdx.x;
  u64 m = 0;
  for (int ci = 0; ci < 64; ci++) {
    float v = fadd(f[ci * 16384 + pix], move[ci]);
    m |= (u64)(v > 0.0f) << ci;
  }
  bo[pix] = m;
}

// --- binary conv + rprelu + residual ---------------------------------------
// Block: 256 thr = 16x4 pixel tile x 4 co-groups (one wave per co-group).
// UPSHUF=false (body): NCHW res/out, u16 bit-pack.  (R13-proven verbatim.)
// UPSHUF=true  (up1/up2): pixel-shuffle, NHWC float4 out, 4x u16 bit-pack;
//   RES_NHWC selects residual layout. Channel order permuted vs body — safe:
//   channels independent, conv sum is integer.
template <int H, int W, int COUT, bool UPSHUF, bool RES_NHWC>
__global__ __launch_bounds__(256) void bconv_kernel(
    const u64* __restrict__ bits_in,   // (nz,H*W) packed acts
    const float* __restrict__ feat,    // residual source
    const u64* __restrict__ wbits,     // (COUT,9)
    const float* __restrict__ scale, const float* __restrict__ pa,
    const float* __restrict__ pb1, const float* __restrict__ pb2,
    const float* __restrict__ nmove,   // (64) next layer's move
    float* __restrict__ out,
    u64* __restrict__ bits_out)
{
  constexpr int NCO = COUT / 4;
  constexpr size_t HW = (size_t)H * W;
  __shared__ u64 s_w[COUT * 9];
  __shared__ float s_sc[COUT], s_a[COUT], s_b1[COUT], s_b2[COUT], s_mv[64];

  int t = threadIdx.x;
  for (int i = t; i < COUT * 9; i += 256) s_w[i] = wbits[i];
  for (int i = t; i < COUT; i += 256) {
    s_sc[i] = scale[i]; s_a[i] = pa[i]; s_b1[i] = pb1[i]; s_b2[i] = pb2[i];
  }
  if (t < 64) s_mv[t] = nmove[t];
  __syncthreads();

  int n = blockIdx.z;
  const u64* bin = bits_in + (size_t)n * HW;
  const float* fin = feat + (size_t)n * 64 * HW;
  float* outp = out + (size_t)n * (UPSHUF ? 256 : 64) * HW;
  u64* bop = bits_out + (size_t)n * (UPSHUF ? 4 : 1) * HW;

  int px = blockIdx.x * 16 + (t & 15);
  int py = blockIdx.y * 4 + ((t >> 4) & 3);
  int cg = t >> 6;                         // wave-uniform co-group
  int pix = py * W + px;

  u64 nb[9];
  int vf = 0, nvalid = 0;
#pragma unroll
  for (int ky = 0; ky < 3; ky++)
#pragma unroll
    for (int kx = 0; kx < 3; kx++) {
      int yy = py + ky - 1, xx = px + kx - 1;
      int tap = ky * 3 + kx;
      u64 m = 0;
      if (yy >= 0 && yy < H && xx >= 0 && xx < W) {
        m = bin[(size_t)yy * W + xx];
        vf |= 1 << tap; nvalid++;
      }
      nb[tap] = m;
    }
  bool interior = (vf == 511);
  int base = 64 * nvalid;

  if constexpr (!UPSHUF) {
    // ---- body path: R13 verbatim ----
    u32 pk = 0;
    for (int jb = 0; jb < NCO; jb += 4) {
#pragma unroll
      for (int s = 0; s < 4; s++) {
        int j = jb + s;
        int co = cg * NCO + j;
        int c = 0;
#pragma unroll
        for (int tap = 0; tap < 9; tap++)
          c += __popcll(nb[tap] ^ s_w[co * 9 + tap]);
        if (!interior) {
#pragma unroll
          for (int tap = 0; tap < 9; tap++)
            if (!((vf >> tap) & 1)) c -= __popcll(s_w[co * 9 + tap]);
        }
        int sint = base - 2 * c;
        float conv = fmul(s_sc[co], (float)sint);
        float t1 = fadd(conv, s_b1[co]);
        float t2 = t1 >= 0.0f ? t1 : fmul(s_a[co], t1);
        float t3 = fadd(t2, s_b2[co]);
        size_t fi = (size_t)co * HW + pix;
        float ov = fadd(t3, fin[fi]);
        outp[fi] = ov;
        pk |= (u32)(fadd(ov, s_mv[co]) > 0.0f) << j;
      }
    }
    ((u16*)bop)[pix * 4 + cg] = (u16)pk;
  } else {
    // ---- up path: NHWC out. co = cg*64 + j, j = ((ob+k)<<2)|sp;
    //      oc = co>>2 = cg*16+ob+k; subpixel sp=(dr,dc). ----
    u32 pk[4] = {0, 0, 0, 0};
    for (int ob = 0; ob < 16; ob += 4) {
#pragma unroll
      for (int sp = 0; sp < 4; sp++) {
        float vq[4];
#pragma unroll
        for (int k = 0; k < 4; k++) {
          int j = ((ob + k) << 2) | sp;
          int co = cg * 64 + j;
          int c = 0;
#pragma unroll
          for (int tap = 0; tap < 9; tap++)
            c += __popcll(nb[tap] ^ s_w[co * 9 + tap]);
          if (!interior) {
#pragma unroll
            for (int tap = 0; tap < 9; tap++)
              if (!((vf >> tap) & 1)) c -= __popcll(s_w[co * 9 + tap]);
          }
          int sint = base - 2 * c;
          float conv = fmul(s_sc[co], (float)sint);
          float t1 = fadd(conv, s_b1[co]);
          float t2 = t1 >= 0.0f ? t1 : fmul(s_a[co], t1);
          float t3 = fadd(t2, s_b2[co]);
          float rv = RES_NHWC ? fin[(size_t)pix * 64 + j]
                              : fin[(size_t)j * HW + pix];
          float ov = fadd(t3, rv);
          vq[k] = ov;
          pk[sp] |= (u32)(fadd(ov, s_mv[cg * 16 + ob + k]) > 0.0f)
                    << (ob + k);
        }
        int dr = sp >> 1, dc = sp & 1;
        size_t opix = (size_t)(2 * py + dr) * (2 * W) + (2 * px + dc);
        float4 v4 = make_float4(vq[0], vq[1], vq[2], vq[3]);
        *(float4*)(outp + opix * 64 + cg * 16 + ob) = v4;
      }
    }
#pragma unroll
    for (int sp = 0; sp < 4; sp++) {
      int dr = sp >> 1, dc = sp & 1;
      size_t opix = (size_t)(2 * py + dr) * (2 * W) + (2 * px + dc);
      ((u16*)bop)[opix * 4 + cg] = (u16)pk[sp];
    }
  }
}

// --- fused hr binary conv + conv_last + bilinear base (NHWC U) -------------
// 16x8 output tile / 128-thr block; 10x18 halo hr output (leaky applied) in
// LDS. R12-proven numerics; NHWC U residual read (base + imm-offset float4)
// removes R12's gather overfetch and address-register spill.
__global__ __launch_bounds__(128) void hrlast_kernel(
    const u64* __restrict__ bits,     // (512*512) packed U + hr_move
    const float* __restrict__ U,      // (512*512,64) NHWC residual
    const u64* __restrict__ hwb, const float* __restrict__ hsc,
    const float* __restrict__ ha, const float* __restrict__ hb1,
    const float* __restrict__ hb2,
    const float* __restrict__ clw, const float* __restrict__ clb,
    const float* __restrict__ x,      // (3,128,128) this sample
    float* __restrict__ out) {        // (3,512,512) this sample
  __shared__ float s_v[180][65];      // [halo pix][ci], +1 pad vs banks
  __shared__ u64 s_wb[576];
  __shared__ float s_sc[64], s_a[64], s_b1[64], s_b2[64];
  __shared__ float s_cw[1728];
  __shared__ float s_cb[3];

  int t = threadIdx.x;
  for (int i = t; i < 576; i += 128) s_wb[i] = hwb[i];
  if (t < 64) { s_sc[t] = hsc[t]; s_a[t] = ha[t]; s_b1[t] = hb1[t]; s_b2[t] = hb2[t]; }
  for (int i = t; i < 1728; i += 128) s_cw[i] = clw[i];
  if (t < 3) s_cb[t] = clb[t];
  __syncthreads();

  int x0 = blockIdx.x * 16, y0 = blockIdx.y * 8;

  // Phase A: hr conv on the 10x18 halo, leaky applied, into LDS
  for (int hp = t; hp < 180; hp += 128) {
    int r = hp / 18, cc = hp - r * 18;
    int gy = y0 - 1 + r, gx = x0 - 1 + cc;
    if (gy < 0 || gy > 511 || gx < 0 || gx > 511) {
      for (int co = 0; co < 64; co++) s_v[hp][co] = 0.0f;
      continue;
    }
    u64 nb[9];
    int vf = 0, nvalid = 0;
#pragma unroll
    for (int ky = 0; ky < 3; ky++)
#pragma unroll
      for (int kx = 0; kx < 3; kx++) {
        int yy = gy + ky - 1, xx = gx + kx - 1;
        int tap = ky * 3 + kx;
        u64 m = 0;
        if (yy >= 0 && yy < 512 && xx >= 0 && xx < 512) {
          m = bits[(size_t)yy * 512 + xx];
          vf |= 1 << tap; nvalid++;
        }
        nb[tap] = m;
      }
    bool interior = (vf == 511);
    int base = 64 * nvalid;
    const float* up = U + ((size_t)gy * 512 + gx) * 64;
    for (int c4 = 0; c4 < 16; c4++) {
      float4 uv = *(const float4*)(up + c4 * 4);
      float us[4] = {uv.x, uv.y, uv.z, uv.w};
#pragma unroll
      for (int q = 0; q < 4; q++) {
        int co = c4 * 4 + q;
        int c = 0;
#pragma unroll
        for (int tap = 0; tap < 9; tap++)
          c += __popcll(nb[tap] ^ s_wb[co * 9 + tap]);
        if (!interior) {
#pragma unroll
          for (int tap = 0; tap < 9; tap++)
            if (!((vf >> tap) & 1)) c -= __popcll(s_wb[co * 9 + tap]);
        }
        int sint = base - 2 * c;
        float conv = fmul(s_sc[co], (float)sint);
        float t1 = fadd(conv, s_b1[co]);
        float t2 = t1 >= 0.0f ? t1 : fmul(s_a[co], t1);
        float t3 = fadd(t2, s_b2[co]);
        float ov = fadd(t3, us[q]);
        s_v[hp][co] = ov >= 0.0f ? ov : fmul(0.1f, ov);  // leaky pre-applied
      }
    }
  }
  __syncthreads();

  // Phase B: conv_last (ky,kx,ci) FMA chain + bias + bilinear base
  int px = t & 15, py = t >> 4;
  int ogx = x0 + px, ogy = y0 + py;
  float a0 = 0.f, a1 = 0.f, a2 = 0.f;
#pragma unroll
  for (int ky = 0; ky < 3; ky++)
#pragma unroll
    for (int kx = 0; kx < 3; kx++) {
      int hp = (py + ky) * 18 + (px + kx);
      int tap = ky * 3 + kx;
      for (int ci = 0; ci < 64; ci++) {
        float v = s_v[hp][ci];
        int k = ci * 9 + tap;
        a0 = fmaf(v, s_cw[k], a0);
        a1 = fmaf(v, s_cw[576 + k], a1);
        a2 = fmaf(v, s_cw[1152 + k], a2);
      }
    }
  float o0 = fadd(a0, s_cb[0]);
  float o1 = fadd(a1, s_cb[1]);
  float o2 = fadd(a2, s_cb[2]);
  float sy = (ogy + 0.5f) * 0.25f - 0.5f;
  float sx = (ogx + 0.5f) * 0.25f - 0.5f;
  int iy0 = (int)floorf(sy);
  int ix0 = (int)floorf(sx);
  float fy = sy - (float)iy0, fx = sx - (float)ix0;
  int y0c = min(max(iy0, 0), 127), y1c = min(max(iy0 + 1, 0), 127);
  int x0c = min(max(ix0, 0), 127), x1c = min(max(ix0 + 1, 0), 127);
  float accs[3] = {o0, o1, o2};
#pragma unroll
  for (int co = 0; co < 3; co++) {
    const float* xp = x + (size_t)co * 16384;
    float c00 = xp[y0c * 128 + x0c], c01 = xp[y0c * 128 + x1c];
    float c10 = xp[y1c * 128 + x0c], c11 = xp[y1c * 128 + x1c];
    float v0, v1;
    if (y1c == y0c) { v0 = fmul(1.f, c00); v1 = fmul(1.f, c01); }
    else {
      v0 = fadd(fmul(1.f - fy, c00), fmul(fy, c10));
      v1 = fadd(fmul(1.f - fy, c01), fmul(fy, c11));
    }
    float base = (x1c == x0c) ? fmul(1.f, v0)
                              : fadd(fmul(1.f - fx, v0), fmul(fx, v1));
    out[((size_t)co << 18) + ((size_t)ogy << 9) + ogx] = fadd(accs[co], base);
  }
}

extern "C" void kernel_launch(void* const* d_in, const int* in_sizes, int n_in,
                              void* d_out, int out_size, void* d_ws,
                              size_t ws_size, hipStream_t stream) {
  const float* x         = (const float*)d_in[0];
  const float* cf_w      = (const float*)d_in[1];
  const float* cf_b      = (const float*)d_in[2];
  const float* body_move = (const float*)d_in[3];
  const float* body_w    = (const float*)d_in[4];
  const float* body_a    = (const float*)d_in[5];
  const float* body_b1   = (const float*)d_in[6];
  const float* body_b2   = (const float*)d_in[7];
  const float* up1_move  = (const float*)d_in[8];
  const float* up1_w     = (const float*)d_in[9];
  const float* up1_a     = (const float*)d_in[10];
  const float* up1_b1    = (const float*)d_in[11];
  const float* up1_b2    = (const float*)d_in[12];
  const float* up2_move  = (const float*)d_in[13];
  const float* up2_w     = (const float*)d_in[14];
  const float* up2_a     = (const float*)d_in[15];
  const float* up2_b1    = (const float*)d_in[16];
  const float* up2_b2    = (const float*)d_in[17];
  const float* hr_move   = (const float*)d_in[18];
  const float* hr_w      = (const float*)d_in[19];
  const float* hr_a      = (const float*)d_in[20];
  const float* hr_b1     = (const float*)d_in[21];
  const float* hr_b2     = (const float*)d_in[22];
  const float* cl_w      = (const float*)d_in[23];
  const float* cl_b      = (const float*)d_in[24];
  float* out = (float*)d_out;

  const size_t M = 1024 * 1024;
  if (ws_size < 160 * M) {
    diag_kernel<<<(out_size + 255) / 256, 256, 0, stream>>>(
        out, out_size, (float)(ws_size >> 20));
    return;
  }

  char* ws = (char*)d_ws;
  float* A    = (float*)(ws + 0);          // (4,64,128,128) NCHW, 16M
  float* B    = (float*)(ws + 16 * M);     // body pong (dead before up1)
  float* Pbat = (float*)(ws + 16 * M);     // (4,256*256,64) NHWC, 64M
  float* U    = (float*)(ws + 80 * M);     // (512*512,64) NHWC per-sample
  u64* bitsA   = (u64*)(ws + 144 * M);     // (4,16384) 512K
  u64* bitsB   = (u64*)(ws + 144 * M + 512 * 1024);
  u64* bits256 = (u64*)(ws + 145 * M);     // (4,65536) 2M
  u64* bits512 = (u64*)(ws + 147 * M);     // (512*512) 2M per-sample
  u64* wbits   = (u64*)(ws + 149 * M);     // 2624*9 u64
  float* scales = (float*)(ws + 150 * M);  // 2624 f32

  // weight prep
  binw_pack_kernel<<<32, 64, 0, stream>>>(body_w, wbits, scales, 2048);
  binw_pack_kernel<<<4, 64, 0, stream>>>(up1_w, wbits + (size_t)2048 * 9,
                                         scales + 2048, 256);
  binw_pack_kernel<<<4, 64, 0, stream>>>(up2_w, wbits + (size_t)2304 * 9,
                                         scales + 2304, 256);
  binw_pack_kernel<<<1, 64, 0, stream>>>(hr_w, wbits + (size_t)2560 * 9,
                                         scales + 2560, 64);

  // head (all samples batched)
  conv_first_kernel<<<dim3(4096, 4), 256, 0, stream>>>(x, cf_w, cf_b, A);
  pack_kernel<<<dim3(64, 4), 256, 0, stream>>>(A, body_move, bitsA);

  // body: 32 BBCU layers, batched over samples (R13-proven)
  float* fin = A;
  float* fout = B;
  u64* bbin = bitsA;
  u64* bbout = bitsB;
  for (int u = 0; u < 32; u++) {
    const float* nm = (u < 31) ? body_move + (u + 1) * 64 : up1_move;
    bconv_kernel<128, 128, 64, false, false>
        <<<dim3(8, 32, 4), 256, 0, stream>>>(
            bbin, fin, wbits + (size_t)u * 576, scales + u * 64,
            body_a + u * 64, body_b1 + u * 64, body_b2 + u * 64, nm,
            fout, bbout);
    float* tf = fin; fin = fout; fout = tf;
    u64* tb = bbin; bbin = bbout; bbout = tb;
  }
  // body out in A (even swap count), its bits (packed w/ up1_move) in bitsA

  // up1 batched: (64,128,128) NCHW -> (256*256,64) NHWC; packs w/ up2_move
  bconv_kernel<128, 128, 256, true, false>
      <<<dim3(8, 32, 4), 256, 0, stream>>>(
          bitsA, A, wbits + (size_t)2048 * 9, scales + 2048,
          up1_a, up1_b1, up1_b2, up2_move, Pbat, bits256);

  // per sample: up2 -> fused hr+conv_last
  for (int n = 0; n < 4; n++) {
    // up2: (256*256,64) NHWC -> (512*512,64) NHWC U; packs bits w/ hr_move
    bconv_kernel<256, 256, 256, true, true>
        <<<dim3(16, 64, 1), 256, 0, stream>>>(
            bits256 + (size_t)n * 65536, Pbat + (size_t)n * 4194304,
            wbits + (size_t)2304 * 9, scales + 2304,
            up2_a, up2_b1, up2_b2, hr_move, U, bits512);
    // fused hr conv + conv_last + bilinear base
    hrlast_kernel<<<dim3(32, 64), 128, 0, stream>>>(
        bits512, U, wbits + (size_t)2560 * 9, scales + 2560,
        hr_a, hr_b1, hr_b2, cl_w, cl_b,
        x + (size_t)n * 49152, out + (size_t)n * 786432);
  }
}

// Round 6
// 1801.208 us; speedup vs baseline: 5.3152x; 5.3152x over previous
//
#include <hip/hip_runtime.h>

// ---------------------------------------------------------------------------
// BBCU binary SR network, round 17 — proven-pieces assembly, no new fusion.
// R12/R16 post-mortem: the fused hr+conv_last kernel is structurally bad
// (256 VGPR + 2GB scratch WRITE + 12% occupancy) regardless of U layout;
// abandoned. This round uses only harness-proven components:
//   * head + 32-layer body: R13/R16 batched dispatches (NCHW, u64 bits).
//   * up1: NCHW residual -> NHWC P (R16-proven UPSHUF path).
//   * up2: NHWC residual -> NHWC U (R16-proven).
//   * hr:  plain bconv, NHWC U residual (float4), V NHWC out with leaky
//          pre-applied (R15-proven V_NHWC path), no bit-pack.
//   * conv_last: NHWC float4 reads, 16x16 tiles (R15-proven).
// ws: A[0,16) B[16,32) body pong | per-sample: P[16,32) NHWC, V[16,80) NHWC
//     (aliases P after consumed), U[80,144) NHWC
//     bitsA/B[144,145) bits256[145,146) bits512[146,148) wbits[149,..)
//     scales[150,..)
// ---------------------------------------------------------------------------

typedef unsigned long long u64;
typedef unsigned int u32;
typedef unsigned short u16;

__device__ inline float fadd(float a, float b) { return __fadd_rn(a, b); }
__device__ inline float fmul(float a, float b) { return __fmul_rn(a, b); }

// numpy pairwise sum of |p[0..n)| (exact numpy algorithm, f32) — for scale
__device__ float pw_abs_sum(const float* p, int n) {
  if (n <= 8) {
    float s = fabsf(p[0]);
    for (int i = 1; i < n; i++) s = fadd(s, fabsf(p[i]));
    return s;
  }
  if (n <= 128) {
    float r[8];
#pragma unroll
    for (int q = 0; q < 8; q++) r[q] = fabsf(p[q]);
    int i;
    for (i = 8; i + 8 <= n; i += 8)
#pragma unroll
      for (int q = 0; q < 8; q++) r[q] = fadd(r[q], fabsf(p[i + q]));
    float res = fadd(fadd(fadd(r[0], r[1]), fadd(r[2], r[3])),
                     fadd(fadd(r[4], r[5]), fadd(r[6], r[7])));
    for (; i < n; i++) res = fadd(res, fabsf(p[i]));
    return res;
  }
  int n2 = (n / 2) & ~7;
  return fadd(pw_abs_sum(p, n2), pw_abs_sum(p + n2, n - n2));
}

// --- diagnostic ------------------------------------------------------------
__global__ __launch_bounds__(256) void diag_kernel(float* __restrict__ out,
                                                   int n, float tag) {
  int idx = blockIdx.x * 256 + threadIdx.x;
  if (idx < n) out[idx] = (idx == 0) ? tag : 0.f;
}

// --- weight prep: scale (numpy pairwise mean|w|) + 9 x u64 sign bits -------
__global__ __launch_bounds__(64) void binw_pack_kernel(
    const float* __restrict__ w, u64* __restrict__ wbits,
    float* __restrict__ scale, int nch) {
  int ch = blockIdx.x * 64 + threadIdx.x;
  if (ch >= nch) return;
  const float* wc = w + (size_t)ch * 576;
  float S = pw_abs_sum(wc, 576);
  scale[ch] = __fdiv_rn(S, 576.0f);
  u64 b[9] = {0, 0, 0, 0, 0, 0, 0, 0, 0};
  for (int ci = 0; ci < 64; ci++) {
#pragma unroll
    for (int tap = 0; tap < 9; tap++)
      b[tap] |= (u64)(wc[ci * 9 + tap] > 0.0f) << ci;
  }
#pragma unroll
  for (int tap = 0; tap < 9; tap++) wbits[(size_t)ch * 9 + tap] = b[tap];
}

// --- conv_first, batched over samples (blockIdx.y = n) ---------------------
__global__ __launch_bounds__(256) void conv_first_kernel(
    const float* __restrict__ x,      // (4,3,128,128)
    const float* __restrict__ w, const float* __restrict__ b,
    float* __restrict__ out) {        // (4,64,128,128)
  int n = blockIdx.y;
  const float* xn = x + (size_t)n * 49152;
  float* on = out + (size_t)n * 1048576;
  int idx = blockIdx.x * 256 + threadIdx.x;
  int gx = idx & 127;
  int gy = (idx >> 7) & 127;
  int co = idx >> 14;
  const float* wp = w + co * 27;
  float acc = 0.f;
  for (int ky = 0; ky < 3; ky++) {
    int yy = gy + ky - 1;
    if (yy < 0 || yy > 127) continue;
    for (int kx = 0; kx < 3; kx++) {
      int xx = gx + kx - 1;
      if (xx < 0 || xx > 127) continue;
      for (int ci = 0; ci < 3; ci++)
        acc = fmaf(xn[ci * 16384 + yy * 128 + xx],
                   wp[ci * 9 + ky * 3 + kx], acc);
    }
  }
  float wb = fadd(acc, b[co]);
  on[idx] = wb >= 0.f ? wb : fmul(0.1f, wb);
}

// --- pack: 64ch f32 + move -> u64 sign bits per pixel (batched) ------------
__global__ __launch_bounds__(256) void pack_kernel(
    const float* __restrict__ feat, const float* __restrict__ move,
    u64* __restrict__ bits) {
  int n = blockIdx.y;
  const float* f = feat + (size_t)n * 1048576;
  u64* bo = bits + (size_t)n * 16384;
  int pix = blockIdx.x * 256 + threadIdx.x;
  u64 m = 0;
  for (int ci = 0; ci < 64; ci++) {
    float v = fadd(f[ci * 16384 + pix], move[ci]);
    m |= (u64)(v > 0.0f) << ci;
  }
  bo[pix] = m;
}

// --- binary conv + rprelu + residual ---------------------------------------
// Block: 256 thr = 16x4 pixel tile x 4 co-groups (one wave per co-group).
// Variants:
//  !UPSHUF && !V_NHWC : body. NCHW res/out, u16 bit-pack. (R13-proven)
//  !UPSHUF &&  V_NHWC : hr. RES_NHWC float4 residual; out = NHWC V with
//                       leaky pre-applied; NO bit-pack. (R15-proven)
//   UPSHUF            : up1/up2. NHWC float4 out, 4x u16 bit-pack;
//                       RES_NHWC selects residual layout. (R16-proven)
template <int H, int W, int COUT, bool UPSHUF, bool RES_NHWC, bool V_NHWC>
__global__ __launch_bounds__(256) void bconv_kernel(
    const u64* __restrict__ bits_in,   // (nz,H*W) packed acts
    const float* __restrict__ feat,    // residual source
    const u64* __restrict__ wbits,     // (COUT,9)
    const float* __restrict__ scale, const float* __restrict__ pa,
    const float* __restrict__ pb1, const float* __restrict__ pb2,
    const float* __restrict__ nmove,   // (64) next layer's move
    float* __restrict__ out,
    u64* __restrict__ bits_out)
{
  constexpr int NCO = COUT / 4;
  constexpr size_t HW = (size_t)H * W;
  __shared__ u64 s_w[COUT * 9];
  __shared__ float s_sc[COUT], s_a[COUT], s_b1[COUT], s_b2[COUT], s_mv[64];

  int t = threadIdx.x;
  for (int i = t; i < COUT * 9; i += 256) s_w[i] = wbits[i];
  for (int i = t; i < COUT; i += 256) {
    s_sc[i] = scale[i]; s_a[i] = pa[i]; s_b1[i] = pb1[i]; s_b2[i] = pb2[i];
  }
  if (t < 64) s_mv[t] = nmove[t];
  __syncthreads();

  int n = blockIdx.z;
  const u64* bin = bits_in + (size_t)n * HW;
  const float* fin = feat + (size_t)n * 64 * HW;
  float* outp = out + (size_t)n * (UPSHUF ? 256 : 64) * HW;
  u64* bop = bits_out ? bits_out + (size_t)n * (UPSHUF ? 4 : 1) * HW
                      : nullptr;

  int px = blockIdx.x * 16 + (t & 15);
  int py = blockIdx.y * 4 + ((t >> 4) & 3);
  int cg = t >> 6;                         // wave-uniform co-group
  int pix = py * W + px;

  u64 nb[9];
  int vf = 0, nvalid = 0;
#pragma unroll
  for (int ky = 0; ky < 3; ky++)
#pragma unroll
    for (int kx = 0; kx < 3; kx++) {
      int yy = py + ky - 1, xx = px + kx - 1;
      int tap = ky * 3 + kx;
      u64 m = 0;
      if (yy >= 0 && yy < H && xx >= 0 && xx < W) {
        m = bin[(size_t)yy * W + xx];
        vf |= 1 << tap; nvalid++;
      }
      nb[tap] = m;
    }
  bool interior = (vf == 511);
  int base = 64 * nvalid;

  if constexpr (!UPSHUF && !V_NHWC) {
    // ---- body path: NCHW, pack ----
    u32 pk = 0;
    for (int jb = 0; jb < NCO; jb += 4) {
#pragma unroll
      for (int s = 0; s < 4; s++) {
        int j = jb + s;
        int co = cg * NCO + j;
        int c = 0;
#pragma unroll
        for (int tap = 0; tap < 9; tap++)
          c += __popcll(nb[tap] ^ s_w[co * 9 + tap]);
        if (!interior) {
#pragma unroll
          for (int tap = 0; tap < 9; tap++)
            if (!((vf >> tap) & 1)) c -= __popcll(s_w[co * 9 + tap]);
        }
        int sint = base - 2 * c;
        float conv = fmul(s_sc[co], (float)sint);
        float t1 = fadd(conv, s_b1[co]);
        float t2 = t1 >= 0.0f ? t1 : fmul(s_a[co], t1);
        float t3 = fadd(t2, s_b2[co]);
        size_t fi = (size_t)co * HW + pix;
        float ov = fadd(t3, fin[fi]);
        outp[fi] = ov;
        pk |= (u32)(fadd(ov, s_mv[co]) > 0.0f) << j;
      }
    }
    ((u16*)bop)[pix * 4 + cg] = (u16)pk;
  } else if constexpr (!UPSHUF && V_NHWC) {
    // ---- hr path: NHWC residual, NHWC V out with leaky, no pack ----
    for (int jb = 0; jb < NCO; jb += 4) {
      float4 uv = *(const float4*)(fin + (size_t)pix * 64 + cg * NCO + jb);
      float us[4] = {uv.x, uv.y, uv.z, uv.w};
      float vq[4];
#pragma unroll
      for (int s = 0; s < 4; s++) {
        int co = cg * NCO + jb + s;
        int c = 0;
#pragma unroll
        for (int tap = 0; tap < 9; tap++)
          c += __popcll(nb[tap] ^ s_w[co * 9 + tap]);
        if (!interior) {
#pragma unroll
          for (int tap = 0; tap < 9; tap++)
            if (!((vf >> tap) & 1)) c -= __popcll(s_w[co * 9 + tap]);
        }
        int sint = base - 2 * c;
        float conv = fmul(s_sc[co], (float)sint);
        float t1 = fadd(conv, s_b1[co]);
        float t2 = t1 >= 0.0f ? t1 : fmul(s_a[co], t1);
        float t3 = fadd(t2, s_b2[co]);
        float ov = fadd(t3, us[s]);
        vq[s] = ov >= 0.0f ? ov : fmul(0.1f, ov);      // leaky pre-applied
      }
      float4 v4 = make_float4(vq[0], vq[1], vq[2], vq[3]);
      *(float4*)(outp + (size_t)pix * 64 + cg * NCO + jb) = v4;
    }
  } else {
    // ---- up path: NHWC out. co = cg*64 + j, j = ((ob+k)<<2)|sp;
    //      oc = co>>2 = cg*16+ob+k; subpixel sp=(dr,dc). ----
    u32 pk[4] = {0, 0, 0, 0};
    for (int ob = 0; ob < 16; ob += 4) {
#pragma unroll
      for (int sp = 0; sp < 4; sp++) {
        float vq[4];
#pragma unroll
        for (int k = 0; k < 4; k++) {
          int j = ((ob + k) << 2) | sp;
          int co = cg * 64 + j;
          int c = 0;
#pragma unroll
          for (int tap = 0; tap < 9; tap++)
            c += __popcll(nb[tap] ^ s_w[co * 9 + tap]);
          if (!interior) {
#pragma unroll
            for (int tap = 0; tap < 9; tap++)
              if (!((vf >> tap) & 1)) c -= __popcll(s_w[co * 9 + tap]);
          }
          int sint = base - 2 * c;
          float conv = fmul(s_sc[co], (float)sint);
          float t1 = fadd(conv, s_b1[co]);
          float t2 = t1 >= 0.0f ? t1 : fmul(s_a[co], t1);
          float t3 = fadd(t2, s_b2[co]);
          float rv = RES_NHWC ? fin[(size_t)pix * 64 + j]
                              : fin[(size_t)j * HW + pix];
          float ov = fadd(t3, rv);
          vq[k] = ov;
          pk[sp] |= (u32)(fadd(ov, s_mv[cg * 16 + ob + k]) > 0.0f)
                    << (ob + k);
        }
        int dr = sp >> 1, dc = sp & 1;
        size_t opix = (size_t)(2 * py + dr) * (2 * W) + (2 * px + dc);
        float4 v4 = make_float4(vq[0], vq[1], vq[2], vq[3]);
        *(float4*)(outp + opix * 64 + cg * 16 + ob) = v4;
      }
    }
#pragma unroll
    for (int sp = 0; sp < 4; sp++) {
      int dr = sp >> 1, dc = sp & 1;
      size_t opix = (size_t)(2 * py + dr) * (2 * W) + (2 * px + dc);
      ((u16*)bop)[opix * 4 + cg] = (u16)pk[sp];
    }
  }
}

// --- conv_last: V is NHWC (512*512, 64) with leaky pre-applied -------------
// 16x16 output tile per 256-thr block; float4 pixel-vector loads.
__global__ __launch_bounds__(256) void conv_last_kernel(
    const float* __restrict__ V,      // (512*512,64) leaky-applied
    const float* __restrict__ w, const float* __restrict__ b,
    const float* __restrict__ x,      // (3,128,128)
    float* __restrict__ out) {        // (3,512,512)
  int t = threadIdx.x;
  int gx = blockIdx.x * 16 + (t & 15);
  int gy = blockIdx.y * 16 + (t >> 4);
  float acc0 = 0.f, acc1 = 0.f, acc2 = 0.f;
  for (int ky = 0; ky < 3; ky++) {             // (ky,kx,ci), ci fastest
    int yy = gy + ky - 1;
    if (yy < 0 || yy > 511) continue;
    for (int kx = 0; kx < 3; kx++) {
      int xx = gx + kx - 1;
      if (xx < 0 || xx > 511) continue;
      int tap = ky * 3 + kx;
      const float4* vp = (const float4*)(V + ((size_t)(yy << 9) + xx) * 64);
#pragma unroll 4
      for (int c4 = 0; c4 < 16; c4++) {
        float4 v = vp[c4];
        int k = (c4 * 4) * 9 + tap;
        acc0 = fmaf(v.x, w[k], acc0);
        acc1 = fmaf(v.x, w[576 + k], acc1);
        acc2 = fmaf(v.x, w[1152 + k], acc2);
        acc0 = fmaf(v.y, w[k + 9], acc0);
        acc1 = fmaf(v.y, w[576 + k + 9], acc1);
        acc2 = fmaf(v.y, w[1152 + k + 9], acc2);
        acc0 = fmaf(v.z, w[k + 18], acc0);
        acc1 = fmaf(v.z, w[576 + k + 18], acc1);
        acc2 = fmaf(v.z, w[1152 + k + 18], acc2);
        acc0 = fmaf(v.w, w[k + 27], acc0);
        acc1 = fmaf(v.w, w[576 + k + 27], acc1);
        acc2 = fmaf(v.w, w[1152 + k + 27], acc2);
      }
    }
  }
  float o0 = fadd(acc0, b[0]);
  float o1 = fadd(acc1, b[1]);
  float o2 = fadd(acc2, b[2]);
  float sy = (gy + 0.5f) * 0.25f - 0.5f;
  float sx = (gx + 0.5f) * 0.25f - 0.5f;
  int iy0 = (int)floorf(sy);
  int ix0 = (int)floorf(sx);
  float fy = sy - (float)iy0, fx = sx - (float)ix0;
  int y0c = min(max(iy0, 0), 127), y1c = min(max(iy0 + 1, 0), 127);
  int x0c = min(max(ix0, 0), 127), x1c = min(max(ix0 + 1, 0), 127);
  float accs[3] = {o0, o1, o2};
#pragma unroll
  for (int co = 0; co < 3; co++) {
    const float* xp = x + (size_t)co * 16384;
    float c00 = xp[y0c * 128 + x0c], c01 = xp[y0c * 128 + x1c];
    float c10 = xp[y1c * 128 + x0c], c11 = xp[y1c * 128 + x1c];
    float v0, v1;
    if (y1c == y0c) { v0 = fmul(1.f, c00); v1 = fmul(1.f, c01); }
    else {
      v0 = fadd(fmul(1.f - fy, c00), fmul(fy, c10));
      v1 = fadd(fmul(1.f - fy, c01), fmul(fy, c11));
    }
    float base = (x1c == x0c) ? fmul(1.f, v0)
                              : fadd(fmul(1.f - fx, v0), fmul(fx, v1));
    out[((size_t)co << 18) + ((size_t)gy << 9) + gx] = fadd(accs[co], base);
  }
}

extern "C" void kernel_launch(void* const* d_in, const int* in_sizes, int n_in,
                              void* d_out, int out_size, void* d_ws,
                              size_t ws_size, hipStream_t stream) {
  const float* x         = (const float*)d_in[0];
  const float* cf_w      = (const float*)d_in[1];
  const float* cf_b      = (const float*)d_in[2];
  const float* body_move = (const float*)d_in[3];
  const float* body_w    = (const float*)d_in[4];
  const float* body_a    = (const float*)d_in[5];
  const float* body_b1   = (const float*)d_in[6];
  const float* body_b2   = (const float*)d_in[7];
  const float* up1_move  = (const float*)d_in[8];
  const float* up1_w     = (const float*)d_in[9];
  const float* up1_a     = (const float*)d_in[10];
  const float* up1_b1    = (const float*)d_in[11];
  const float* up1_b2    = (const float*)d_in[12];
  const float* up2_move  = (const float*)d_in[13];
  const float* up2_w     = (const float*)d_in[14];
  const float* up2_a     = (const float*)d_in[15];
  const float* up2_b1    = (const float*)d_in[16];
  const float* up2_b2    = (const float*)d_in[17];
  const float* hr_move   = (const float*)d_in[18];
  const float* hr_w      = (const float*)d_in[19];
  const float* hr_a      = (const float*)d_in[20];
  const float* hr_b1     = (const float*)d_in[21];
  const float* hr_b2     = (const float*)d_in[22];
  const float* cl_w      = (const float*)d_in[23];
  const float* cl_b      = (const float*)d_in[24];
  float* out = (float*)d_out;

  const size_t M = 1024 * 1024;
  if (ws_size < 160 * M) {
    diag_kernel<<<(out_size + 255) / 256, 256, 0, stream>>>(
        out, out_size, (float)(ws_size >> 20));
    return;
  }

  char* ws = (char*)d_ws;
  float* A    = (float*)(ws + 0);          // (4,64,128,128) NCHW, 16M
  float* B    = (float*)(ws + 16 * M);     // body pong (dead before up1)
  float* P    = (float*)(ws + 16 * M);     // (256*256,64) NHWC per-sample
  float* V    = (float*)(ws + 16 * M);     // (512*512,64) NHWC per-sample
                                           //   (aliases P after P consumed)
  float* U    = (float*)(ws + 80 * M);     // (512*512,64) NHWC per-sample
  u64* bitsA   = (u64*)(ws + 144 * M);     // (4,16384) 512K
  u64* bitsB   = (u64*)(ws + 144 * M + 512 * 1024);
  u64* bits256 = (u64*)(ws + 145 * M);     // (256*256) per-sample 512K
  u64* bits512 = (u64*)(ws + 146 * M);     // (512*512) 2M per-sample
  u64* wbits   = (u64*)(ws + 149 * M);     // 2624*9 u64
  float* scales = (float*)(ws + 150 * M);  // 2624 f32

  // weight prep
  binw_pack_kernel<<<32, 64, 0, stream>>>(body_w, wbits, scales, 2048);
  binw_pack_kernel<<<4, 64, 0, stream>>>(up1_w, wbits + (size_t)2048 * 9,
                                         scales + 2048, 256);
  binw_pack_kernel<<<4, 64, 0, stream>>>(up2_w, wbits + (size_t)2304 * 9,
                                         scales + 2304, 256);
  binw_pack_kernel<<<1, 64, 0, stream>>>(hr_w, wbits + (size_t)2560 * 9,
                                         scales + 2560, 64);

  // head (all samples batched)
  conv_first_kernel<<<dim3(4096, 4), 256, 0, stream>>>(x, cf_w, cf_b, A);
  pack_kernel<<<dim3(64, 4), 256, 0, stream>>>(A, body_move, bitsA);

  // body: 32 BBCU layers, batched over samples (R13-proven)
  float* fin = A;
  float* fout = B;
  u64* bbin = bitsA;
  u64* bbout = bitsB;
  for (int u = 0; u < 32; u++) {
    const float* nm = (u < 31) ? body_move + (u + 1) * 64 : up1_move;
    bconv_kernel<128, 128, 64, false, false, false>
        <<<dim3(8, 32, 4), 256, 0, stream>>>(
            bbin, fin, wbits + (size_t)u * 576, scales + u * 64,
            body_a + u * 64, body_b1 + u * 64, body_b2 + u * 64, nm,
            fout, bbout);
    float* tf = fin; fin = fout; fout = tf;
    u64* tb = bbin; bbin = bbout; bbout = tb;
  }
  // body out in A (even swap count), its bits (packed w/ up1_move) in bitsA

  // per sample: up1 -> up2 -> hr -> conv_last
  for (int n = 0; n < 4; n++) {
    // up1: NCHW res (64,128,128) -> NHWC P (256*256,64); bits w/ up2_move
    bconv_kernel<128, 128, 256, true, false, false>
        <<<dim3(8, 32, 1), 256, 0, stream>>>(
            bitsA + (size_t)n * 16384, A + (size_t)n * 1048576,
            wbits + (size_t)2048 * 9, scales + 2048,
            up1_a, up1_b1, up1_b2, up2_move, P, bits256);
    // up2: NHWC res P -> NHWC U (512*512,64); bits w/ hr_move
    bconv_kernel<256, 256, 256, true, true, false>
        <<<dim3(16, 64, 1), 256, 0, stream>>>(
            bits256, P, wbits + (size_t)2304 * 9, scales + 2304,
            up2_a, up2_b1, up2_b2, hr_move, U, bits512);
    // hr: NHWC U residual -> V NHWC with leaky pre-applied (P dead)
    bconv_kernel<512, 512, 64, false, true, true>
        <<<dim3(32, 128, 1), 256, 0, stream>>>(
            bits512, U, wbits + (size_t)2560 * 9, scales + 2560,
            hr_a, hr_b1, hr_b2, hr_move, V, nullptr);
    // conv_last + bilinear base (16x16 tiles, float4 NHWC reads)
    conv_last_kernel<<<dim3(32, 32), 256, 0, stream>>>(
        V, cl_w, cl_b, x + (size_t)n * 49152,
        out + (size_t)n * 786432);
  }
}